// Round 8
// baseline (2064.139 us; speedup 1.0000x reference)
//
#include <hip/hip_runtime.h>

#define N_ROWS 65536
#define DIM    512
#define NSTEP  10

typedef float  f32x16 __attribute__((ext_vector_type(16)));
typedef float  f32x4  __attribute__((ext_vector_type(4)));
typedef short  s16x8  __attribute__((ext_vector_type(8)));
typedef __bf16 bf16x8 __attribute__((ext_vector_type(8)));
typedef unsigned int u32x2 __attribute__((ext_vector_type(2)));
typedef unsigned int u32x4 __attribute__((ext_vector_type(4)));

__device__ __forceinline__ unsigned f2bf(float f) {
  unsigned u = __float_as_uint(f);
  return (u + 0x7fffu + ((u >> 16) & 1u)) >> 16;  // exact RNE fp32 -> bf16
}
// nearest rounding (ties away from zero), packed via v_perm
__device__ __forceinline__ unsigned pack2bf_rn(float a, float b) {
  unsigned ua = __float_as_uint(a) + 0x8000u;
  unsigned ub = __float_as_uint(b) + 0x8000u;
  return __builtin_amdgcn_perm(ub, ua, 0x07060302u);
}
#define LOG2E_X2 2.885390081777927f
#define LOG2E    1.442695040888963f
__device__ __forceinline__ float ftanh(float x) {   // 1 - 2/(1+2^(2x*log2e))
  float t = __builtin_amdgcn_exp2f(x * LOG2E_X2);
  float r = __builtin_amdgcn_rcpf(1.0f + t);
  return __builtin_fmaf(-2.0f, r, 1.0f);
}
__device__ __forceinline__ float fsigm(float x) {
  float t = __builtin_amdgcn_exp2f(-x * LOG2E);
  return __builtin_amdgcn_rcpf(1.0f + t);
}
__device__ __forceinline__ void mfma(f32x16& c, s16x8 a, s16x8 b) {
  c = __builtin_amdgcn_mfma_f32_32x32x16_bf16(
        __builtin_bit_cast(bf16x8, a), __builtin_bit_cast(bf16x8, b), c, 0, 0, 0);
}

// Pack a 512x512 slice of row-major fp32 weights into bf16 MFMA A-frags,
// OTG-MAJOR streams: frag f = otg*32 + ks holds
// A[o=otg*32+(l&31)][k=ks*16+8*(l>>5)+i], i=0..7.  Wave w's stream = 32KB
// contiguous at f in [32w, 32w+32).
__global__ void pack_frags_kernel(const float* __restrict__ src, int row_stride,
                                  int col_off, unsigned short* __restrict__ dst) {
  const int idx = blockIdx.x * 256 + threadIdx.x;  // 0..32767
  const int l    = idx & 63;
  const int frag = idx >> 6;        // otg*32 + ks
  const int otg  = frag >> 5;
  const int ks   = frag & 31;
  const int o = otg * 32 + (l & 31);
  const int k = ks * 16 + (l >> 5) * 8;
  const float* p = src + (size_t)o * row_stride + col_off + k;
  s16x8 v;
#pragma unroll
  for (int i = 0; i < 8; ++i) v[i] = (short)f2bf(p[i]);
  *reinterpret_cast<s16x8*>(dst + (size_t)idx * 8) = v;
}

// c1[s][o] = b1[o] + t_s * W1[o][512]   (time-column folded into step bias)
__global__ void c1_kernel(const float* __restrict__ W1, const float* __restrict__ b1,
                          float* __restrict__ c1) {
  const int o = threadIdx.x;  // 512 threads
  const float wt = W1[(size_t)o * 513 + 512];
  const float bb = b1[o];
  for (int s = 0; s < NSTEP; ++s)
    c1[s * DIM + o] = bb + ((float)s * 0.1f) * wt;
}

// 1024 threads = 16 waves; wave w owns o-cols [32w, 32w+32) x all 64 m rows.
// LDS tile stored in B-frag layout: frag(ks,mt) @ (ks*2+mt)*1024, lane l's 16B
// at l*16 holding tile[m=32mt+(l&31)][k=16ks+8*(l>>5)+i].
__global__ __launch_bounds__(1024)
void ode_fused(const float* __restrict__ x, const float* __restrict__ h0,
               const float* __restrict__ b2, const float* __restrict__ bg,
               const s16x8* __restrict__ w1f, const s16x8* __restrict__ w2f,
               const s16x8* __restrict__ wgaf, const s16x8* __restrict__ wgbf,
               const float* __restrict__ c1, float* __restrict__ out)
{
  __shared__ char ldsT[64 * 1024];   // 64 frags of 1KB, in-place

  const int tid = threadIdx.x;
  const int w   = tid >> 6;          // wave 0..15, owns otg = w
  const int l   = tid & 63;
  const int lm  = l & 31;
  const int h5  = l >> 5;
  const int m0  = blockIdx.x << 6;   // 64 rows per block
  const int ow  = w << 5;            // 32-wide o-column range
  const unsigned lbyte = (unsigned)l << 4;

  // ---------------- stage h0 -> ldsT in frag layout ----------------
  {
#pragma unroll
    for (int q = 0; q < 2; ++q) {
      const int ks = (w << 1) | q;
#pragma unroll
      for (int mt = 0; mt < 2; ++mt) {
        const float* src = h0 + (size_t)(m0 + (mt << 5) + lm) * DIM + (ks << 4) + (h5 << 3);
        f32x4 v0 = *reinterpret_cast<const f32x4*>(src);
        f32x4 v1 = *reinterpret_cast<const f32x4*>(src + 4);
        u32x4 pk;
        pk[0] = pack2bf_rn(v0[0], v0[1]); pk[1] = pack2bf_rn(v0[2], v0[3]);
        pk[2] = pack2bf_rn(v1[0], v1[1]); pk[3] = pack2bf_rn(v1[2], v1[3]);
        *reinterpret_cast<u32x4*>(ldsT + (((ks << 1) | mt) << 10) + lbyte) = pk;
      }
    }
  }

  // ---------------- fp32 h state in acc layout ----------------
  // value (mt, reg=4g+j): m = m0+32*mt+lm, o = ow+8g+4*h5+j
  f32x16 hst[2];
#pragma unroll
  for (int mt = 0; mt < 2; ++mt) {
    const float* hr = h0 + (size_t)(m0 + (mt << 5) + lm) * DIM;
#pragma unroll
    for (int g = 0; g < 4; ++g) {
      const int oc = ow + (g << 3) + (h5 << 2);
      f32x4 v = *reinterpret_cast<const f32x4*>(hr + oc);
#pragma unroll
      for (int j = 0; j < 4; ++j) hst[mt][(g << 2) + j] = v[j];
    }
  }

  f32x16 acc[2];

  // acc[mt][o][m] += W[o][k] * tile[m][k] over K=512; address-free K-loop:
  // A: per-wave contiguous stream; B: literal ds offsets from one base.
  auto mm_lds = [&](const s16x8* __restrict__ A) {
    const s16x8* Aw = A + (w << 11);   // otg=w stream, 32KB
#pragma unroll
    for (int ks = 0; ks < 32; ++ks) {
      s16x8 a  = Aw[(ks << 6) + l];
      s16x8 b0 = *reinterpret_cast<const s16x8*>(ldsT + (ks << 11) + lbyte);
      s16x8 b1 = *reinterpret_cast<const s16x8*>(ldsT + (ks << 11) + 1024 + lbyte);
      mfma(acc[0], a, b0);
      mfma(acc[1], a, b1);
    }
  };

  // broadcast per-o fp32 vector into acc
  auto acc_init = [&](const float* __restrict__ vec) {
#pragma unroll
    for (int g = 0; g < 4; ++g) {
      const int oc = ow + (g << 3) + (h5 << 2);
      f32x4 v = *reinterpret_cast<const f32x4*>(vec + oc);
#pragma unroll
      for (int j = 0; j < 4; ++j) {
        acc[0][(g << 2) + j] = v[j];
        acc[1][(g << 2) + j] = v[j];
      }
    }
  };

  // write bf16(src) into tile frag layout (k-dim = this wave's o columns).
  // Value (mt, 4g+j): dest frag(ks=2w+(g>>1), mt), lane lm+32*(g&1), byte 8*h5.
  auto tile_write = [&](const f32x16 src[2]) {
    const unsigned base = ((unsigned)w << 12) + ((unsigned)lm << 4) + ((unsigned)h5 << 3);
#pragma unroll
    for (int mt = 0; mt < 2; ++mt)
#pragma unroll
      for (int g = 0; g < 4; ++g) {
        u32x2 pk;
        pk[0] = pack2bf_rn(src[mt][(g << 2) + 0], src[mt][(g << 2) + 1]);
        pk[1] = pack2bf_rn(src[mt][(g << 2) + 2], src[mt][(g << 2) + 3]);
        *reinterpret_cast<u32x2*>(ldsT + base + ((g >> 1) << 11) + (mt << 10) + ((g & 1) << 9)) = pk;
      }
  };

  __syncthreads();  // staged tile visible

  for (int s = 0; s < NSTEP; ++s) {
    // H1 = tanh(W1 . Z^T + c1_s)
    acc_init(c1 + s * DIM);
    mm_lds(w1f);
#pragma unroll
    for (int mt = 0; mt < 2; ++mt)
#pragma unroll
      for (int i = 0; i < 16; ++i) acc[mt][i] = ftanh(acc[mt][i]);
    __syncthreads();          // all reads of Z done
    tile_write(acc);          // overwrite in place with H1
    __syncthreads();          // H1 visible
    // h += dt * tanh(W2 . H1^T + b2)  == fma(-0.2, rcp(1+e^{2a}), h+0.1)
    acc_init(b2);
    mm_lds(w2f);
#pragma unroll
    for (int mt = 0; mt < 2; ++mt)
#pragma unroll
      for (int i = 0; i < 16; ++i) {
        float t = __builtin_amdgcn_exp2f(acc[mt][i] * LOG2E_X2);
        float r = __builtin_amdgcn_rcpf(1.0f + t);
        hst[mt][i] = __builtin_fmaf(-0.2f, r, hst[mt][i] + 0.1f);
      }
    __syncthreads();          // all reads of H1 done
    tile_write(hst);          // overwrite in place with new h
    __syncthreads();          // h visible
  }

  // ---- gating: G = WgB . E^T + WgA . X^T + bg ----
  acc_init(bg);
  mm_lds(wgbf);        // evolved part (tile holds E)
  {
    const s16x8* Aw = wgaf + (w << 11);
    const float* xr0 = x + (size_t)(m0 + lm) * DIM + (h5 << 3);
    const float* xr1 = xr0 + (size_t)32 * DIM;
#pragma unroll 4
    for (int ks = 0; ks < 32; ++ks) {
      s16x8 a = Aw[(ks << 6) + l];
      const int kc = ks << 4;
      f32x4 u0 = *reinterpret_cast<const f32x4*>(xr0 + kc);
      f32x4 u1 = *reinterpret_cast<const f32x4*>(xr0 + kc + 4);
      u32x4 pb;
      pb[0] = pack2bf_rn(u0[0], u0[1]); pb[1] = pack2bf_rn(u0[2], u0[3]);
      pb[2] = pack2bf_rn(u1[0], u1[1]); pb[3] = pack2bf_rn(u1[2], u1[3]);
      s16x8 b0 = __builtin_bit_cast(s16x8, pb);
      f32x4 w0 = *reinterpret_cast<const f32x4*>(xr1 + kc);
      f32x4 w1 = *reinterpret_cast<const f32x4*>(xr1 + kc + 4);
      u32x4 qb;
      qb[0] = pack2bf_rn(w0[0], w0[1]); qb[1] = pack2bf_rn(w0[2], w0[3]);
      qb[2] = pack2bf_rn(w1[0], w1[1]); qb[3] = pack2bf_rn(w1[2], w1[3]);
      s16x8 b1 = __builtin_bit_cast(s16x8, qb);
      mfma(acc[0], a, b0);
      mfma(acc[1], a, b1);
    }
  }

  // ---- blend + store both output copies ----
  float* out1 = out + (size_t)N_ROWS * DIM;
#pragma unroll
  for (int mt = 0; mt < 2; ++mt) {
    const int m = m0 + (mt << 5) + lm;
    const float* xr = x + (size_t)m * DIM;
    float* o0p = out  + (size_t)m * DIM;
    float* o1p = out1 + (size_t)m * DIM;
#pragma unroll
    for (int g = 0; g < 4; ++g) {
      const int oc = ow + (g << 3) + (h5 << 2);
      f32x4 xv = *reinterpret_cast<const f32x4*>(xr + oc);
      f32x4 r;
#pragma unroll
      for (int j = 0; j < 4; ++j) {
        const float gt = fsigm(acc[mt][(g << 2) + j]);
        const float ev = hst[mt][(g << 2) + j];
        r[j] = gt * ev + (1.0f - gt) * xv[j];
      }
      *reinterpret_cast<f32x4*>(o0p + oc) = r;
      *reinterpret_cast<f32x4*>(o1p + oc) = r;
    }
  }
}

extern "C" void kernel_launch(void* const* d_in, const int* in_sizes, int n_in,
                              void* d_out, int out_size, void* d_ws, size_t ws_size,
                              hipStream_t stream) {
  const float* x  = (const float*)d_in[0];
  const float* h0 = (const float*)d_in[1];
  const float* W1 = (const float*)d_in[2];
  const float* b1 = (const float*)d_in[3];
  const float* W2 = (const float*)d_in[4];
  const float* b2 = (const float*)d_in[5];
  const float* Wg = (const float*)d_in[6];
  const float* bg = (const float*)d_in[7];

  char* ws = (char*)d_ws;
  const size_t FRAG_BYTES = (size_t)512 * 512 * 2;  // 512 KB each
  unsigned short* w1f  = (unsigned short*)(ws + 0 * FRAG_BYTES);
  unsigned short* w2f  = (unsigned short*)(ws + 1 * FRAG_BYTES);
  unsigned short* wgaf = (unsigned short*)(ws + 2 * FRAG_BYTES);
  unsigned short* wgbf = (unsigned short*)(ws + 3 * FRAG_BYTES);
  float*          c1   = (float*)(ws + 4 * FRAG_BYTES);

  pack_frags_kernel<<<128, 256, 0, stream>>>(W1, 513, 0,   w1f);
  pack_frags_kernel<<<128, 256, 0, stream>>>(W2, 512, 0,   w2f);
  pack_frags_kernel<<<128, 256, 0, stream>>>(Wg, 1024, 0,  wgaf);
  pack_frags_kernel<<<128, 256, 0, stream>>>(Wg, 1024, 512, wgbf);
  c1_kernel<<<1, 512, 0, stream>>>(W1, b1, c1);

  ode_fused<<<N_ROWS / 64, 1024, 0, stream>>>(x, h0, b2, bg,
                                              (const s16x8*)w1f, (const s16x8*)w2f,
                                              (const s16x8*)wgaf, (const s16x8*)wgbf,
                                              c1, (float*)d_out);
}

// Round 9
// 1084.380 us; speedup vs baseline: 1.9035x; 1.9035x over previous
//
#include <hip/hip_runtime.h>

#define N_ROWS 65536
#define DIM    512
#define NSTEP  10

typedef float  f32x16 __attribute__((ext_vector_type(16)));
typedef float  f32x4  __attribute__((ext_vector_type(4)));
typedef short  s16x8  __attribute__((ext_vector_type(8)));
typedef __bf16 bf16x8 __attribute__((ext_vector_type(8)));
typedef unsigned int u32x2 __attribute__((ext_vector_type(2)));
typedef unsigned int u32x4 __attribute__((ext_vector_type(4)));

__device__ __forceinline__ unsigned f2bf(float f) {
  unsigned u = __float_as_uint(f);
  return (u + 0x7fffu + ((u >> 16) & 1u)) >> 16;  // exact RNE fp32 -> bf16
}
// nearest rounding (ties away from zero), packed via v_perm
__device__ __forceinline__ unsigned pack2bf_rn(float a, float b) {
  unsigned ua = __float_as_uint(a) + 0x8000u;
  unsigned ub = __float_as_uint(b) + 0x8000u;
  return __builtin_amdgcn_perm(ub, ua, 0x07060302u);
}
#define LOG2E_X2 2.885390081777927f
#define LOG2E    1.442695040888963f
__device__ __forceinline__ float ftanh(float x) {   // 1 - 2/(1+2^(2x*log2e))
  float t = __builtin_amdgcn_exp2f(x * LOG2E_X2);
  float r = __builtin_amdgcn_rcpf(1.0f + t);
  return __builtin_fmaf(-2.0f, r, 1.0f);
}
__device__ __forceinline__ float fsigm(float x) {
  float t = __builtin_amdgcn_exp2f(-x * LOG2E);
  return __builtin_amdgcn_rcpf(1.0f + t);
}
__device__ __forceinline__ void mfma(f32x16& c, s16x8 a, s16x8 b) {
  c = __builtin_amdgcn_mfma_f32_32x32x16_bf16(
        __builtin_bit_cast(bf16x8, a), __builtin_bit_cast(bf16x8, b), c, 0, 0, 0);
}

// Pack a 512x512 slice of row-major fp32 weights into bf16 MFMA A-frags,
// OTG-MAJOR streams: frag f = otg*32 + ks holds
// A[o=otg*32+(l&31)][k=ks*16+8*(l>>5)+i], i=0..7.  Wave w's stream = 32KB
// contiguous at f in [32w, 32w+32).
__global__ void pack_frags_kernel(const float* __restrict__ src, int row_stride,
                                  int col_off, unsigned short* __restrict__ dst) {
  const int idx = blockIdx.x * 256 + threadIdx.x;  // 0..32767
  const int l    = idx & 63;
  const int frag = idx >> 6;        // otg*32 + ks
  const int otg  = frag >> 5;
  const int ks   = frag & 31;
  const int o = otg * 32 + (l & 31);
  const int k = ks * 16 + (l >> 5) * 8;
  const float* p = src + (size_t)o * row_stride + col_off + k;
  s16x8 v;
#pragma unroll
  for (int i = 0; i < 8; ++i) v[i] = (short)f2bf(p[i]);
  *reinterpret_cast<s16x8*>(dst + (size_t)idx * 8) = v;
}

// c1[s][o] = b1[o] + t_s * W1[o][512]   (time-column folded into step bias)
__global__ void c1_kernel(const float* __restrict__ W1, const float* __restrict__ b1,
                          float* __restrict__ c1) {
  const int o = threadIdx.x;  // 512 threads
  const float wt = W1[(size_t)o * 513 + 512];
  const float bb = b1[o];
  for (int s = 0; s < NSTEP; ++s)
    c1[s * DIM + o] = bb + ((float)s * 0.1f) * wt;
}

// 1024 threads = 16 waves; wave w owns o-cols [32w, 32w+32) x all 64 m rows.
// LDS tile stored in B-frag layout: frag(ks,mt) @ (ks*2+mt)*1024, lane l's 16B
// at l*16 holding tile[m=32mt+(l&31)][k=16ks+8*(l>>5)+i].
__global__ __launch_bounds__(1024)
void ode_fused(const float* __restrict__ x, const float* __restrict__ h0,
               const float* __restrict__ b2, const float* __restrict__ bg,
               const s16x8* __restrict__ w1f, const s16x8* __restrict__ w2f,
               const s16x8* __restrict__ wgaf, const s16x8* __restrict__ wgbf,
               const float* __restrict__ c1, float* __restrict__ out)
{
  __shared__ char ldsT[64 * 1024];   // 64 frags of 1KB, in-place

  const int tid = threadIdx.x;
  const int w   = tid >> 6;          // wave 0..15, owns otg = w
  const int l   = tid & 63;
  const int lm  = l & 31;
  const int h5  = l >> 5;
  const int m0  = blockIdx.x << 6;   // 64 rows per block
  const int ow  = w << 5;            // 32-wide o-column range
  const unsigned lbyte = (unsigned)l << 4;

  // ---------------- stage h0 -> ldsT in frag layout ----------------
  {
#pragma unroll
    for (int q = 0; q < 2; ++q) {
      const int ks = (w << 1) | q;
#pragma unroll
      for (int mt = 0; mt < 2; ++mt) {
        const float* src = h0 + (size_t)(m0 + (mt << 5) + lm) * DIM + (ks << 4) + (h5 << 3);
        f32x4 v0 = *reinterpret_cast<const f32x4*>(src);
        f32x4 v1 = *reinterpret_cast<const f32x4*>(src + 4);
        u32x4 pk;
        pk[0] = pack2bf_rn(v0[0], v0[1]); pk[1] = pack2bf_rn(v0[2], v0[3]);
        pk[2] = pack2bf_rn(v1[0], v1[1]); pk[3] = pack2bf_rn(v1[2], v1[3]);
        *reinterpret_cast<u32x4*>(ldsT + (((ks << 1) | mt) << 10) + lbyte) = pk;
      }
    }
  }

  // ---------------- fp32 h state in acc layout ----------------
  // value (mt, reg=4g+j): m = m0+32*mt+lm, o = ow+8g+4*h5+j
  f32x16 hst[2];
#pragma unroll
  for (int mt = 0; mt < 2; ++mt) {
    const float* hr = h0 + (size_t)(m0 + (mt << 5) + lm) * DIM;
#pragma unroll
    for (int g = 0; g < 4; ++g) {
      const int oc = ow + (g << 3) + (h5 << 2);
      f32x4 v = *reinterpret_cast<const f32x4*>(hr + oc);
#pragma unroll
      for (int j = 0; j < 4; ++j) hst[mt][(g << 2) + j] = v[j];
    }
  }

  f32x16 acc[2];

  // acc[mt][o][m] += W[o][k] * tile[m][k] over K=512; address-free K-loop:
  // A: per-wave contiguous stream; B: literal ds offsets from one base.
  // unroll 4 (NOT full): caps live regs -> no scratch spill (R8 lesson).
  auto mm_lds = [&](const s16x8* __restrict__ A) {
    const s16x8* Aw = A + (w << 11);   // otg=w stream, 32KB
#pragma unroll 4
    for (int ks = 0; ks < 32; ++ks) {
      s16x8 a  = Aw[(ks << 6) + l];
      s16x8 b0 = *reinterpret_cast<const s16x8*>(ldsT + (ks << 11) + lbyte);
      s16x8 b1 = *reinterpret_cast<const s16x8*>(ldsT + (ks << 11) + 1024 + lbyte);
      mfma(acc[0], a, b0);
      mfma(acc[1], a, b1);
    }
  };

  // broadcast per-o fp32 vector into acc
  auto acc_init = [&](const float* __restrict__ vec) {
#pragma unroll
    for (int g = 0; g < 4; ++g) {
      const int oc = ow + (g << 3) + (h5 << 2);
      f32x4 v = *reinterpret_cast<const f32x4*>(vec + oc);
#pragma unroll
      for (int j = 0; j < 4; ++j) {
        acc[0][(g << 2) + j] = v[j];
        acc[1][(g << 2) + j] = v[j];
      }
    }
  };

  // write bf16(src) into tile frag layout (k-dim = this wave's o columns).
  // Value (mt, 4g+j): dest frag(ks=2w+(g>>1), mt), lane lm+32*(g&1), byte 8*h5.
  auto tile_write = [&](const f32x16 src[2]) {
    const unsigned base = ((unsigned)w << 12) + ((unsigned)lm << 4) + ((unsigned)h5 << 3);
#pragma unroll
    for (int mt = 0; mt < 2; ++mt)
#pragma unroll
      for (int g = 0; g < 4; ++g) {
        u32x2 pk;
        pk[0] = pack2bf_rn(src[mt][(g << 2) + 0], src[mt][(g << 2) + 1]);
        pk[1] = pack2bf_rn(src[mt][(g << 2) + 2], src[mt][(g << 2) + 3]);
        *reinterpret_cast<u32x2*>(ldsT + base + ((g >> 1) << 11) + (mt << 10) + ((g & 1) << 9)) = pk;
      }
  };

  __syncthreads();  // staged tile visible

#pragma unroll 1
  for (int s = 0; s < NSTEP; ++s) {
    // H1 = tanh(W1 . Z^T + c1_s)
    acc_init(c1 + s * DIM);
    mm_lds(w1f);
#pragma unroll
    for (int mt = 0; mt < 2; ++mt)
#pragma unroll
      for (int i = 0; i < 16; ++i) acc[mt][i] = ftanh(acc[mt][i]);
    __syncthreads();          // all reads of Z done
    tile_write(acc);          // overwrite in place with H1
    __syncthreads();          // H1 visible
    // h += dt * tanh(W2 . H1^T + b2)  == fma(-0.2, rcp(1+e^{2a}), h+0.1)
    acc_init(b2);
    mm_lds(w2f);
#pragma unroll
    for (int mt = 0; mt < 2; ++mt)
#pragma unroll
      for (int i = 0; i < 16; ++i) {
        float t = __builtin_amdgcn_exp2f(acc[mt][i] * LOG2E_X2);
        float r = __builtin_amdgcn_rcpf(1.0f + t);
        hst[mt][i] = __builtin_fmaf(-0.2f, r, hst[mt][i] + 0.1f);
      }
    __syncthreads();          // all reads of H1 done
    tile_write(hst);          // overwrite in place with new h
    __syncthreads();          // h visible
  }

  // ---- gating: G = WgB . E^T + WgA . X^T + bg ----
  acc_init(bg);
  mm_lds(wgbf);        // evolved part (tile holds E)
  {
    const s16x8* Aw = wgaf + (w << 11);
    const float* xr0 = x + (size_t)(m0 + lm) * DIM + (h5 << 3);
    const float* xr1 = xr0 + (size_t)32 * DIM;
#pragma unroll 4
    for (int ks = 0; ks < 32; ++ks) {
      s16x8 a = Aw[(ks << 6) + l];
      const int kc = ks << 4;
      f32x4 u0 = *reinterpret_cast<const f32x4*>(xr0 + kc);
      f32x4 u1 = *reinterpret_cast<const f32x4*>(xr0 + kc + 4);
      u32x4 pb;
      pb[0] = pack2bf_rn(u0[0], u0[1]); pb[1] = pack2bf_rn(u0[2], u0[3]);
      pb[2] = pack2bf_rn(u1[0], u1[1]); pb[3] = pack2bf_rn(u1[2], u1[3]);
      s16x8 b0 = __builtin_bit_cast(s16x8, pb);
      f32x4 w0 = *reinterpret_cast<const f32x4*>(xr1 + kc);
      f32x4 w1 = *reinterpret_cast<const f32x4*>(xr1 + kc + 4);
      u32x4 qb;
      qb[0] = pack2bf_rn(w0[0], w0[1]); qb[1] = pack2bf_rn(w0[2], w0[3]);
      qb[2] = pack2bf_rn(w1[0], w1[1]); qb[3] = pack2bf_rn(w1[2], w1[3]);
      s16x8 b1 = __builtin_bit_cast(s16x8, qb);
      mfma(acc[0], a, b0);
      mfma(acc[1], a, b1);
    }
  }

  // ---- blend + store both output copies ----
  float* out1 = out + (size_t)N_ROWS * DIM;
#pragma unroll
  for (int mt = 0; mt < 2; ++mt) {
    const int m = m0 + (mt << 5) + lm;
    const float* xr = x + (size_t)m * DIM;
    float* o0p = out  + (size_t)m * DIM;
    float* o1p = out1 + (size_t)m * DIM;
#pragma unroll
    for (int g = 0; g < 4; ++g) {
      const int oc = ow + (g << 3) + (h5 << 2);
      f32x4 xv = *reinterpret_cast<const f32x4*>(xr + oc);
      f32x4 r;
#pragma unroll
      for (int j = 0; j < 4; ++j) {
        const float gt = fsigm(acc[mt][(g << 2) + j]);
        const float ev = hst[mt][(g << 2) + j];
        r[j] = gt * ev + (1.0f - gt) * xv[j];
      }
      *reinterpret_cast<f32x4*>(o0p + oc) = r;
      *reinterpret_cast<f32x4*>(o1p + oc) = r;
    }
  }
}

extern "C" void kernel_launch(void* const* d_in, const int* in_sizes, int n_in,
                              void* d_out, int out_size, void* d_ws, size_t ws_size,
                              hipStream_t stream) {
  const float* x  = (const float*)d_in[0];
  const float* h0 = (const float*)d_in[1];
  const float* W1 = (const float*)d_in[2];
  const float* b1 = (const float*)d_in[3];
  const float* W2 = (const float*)d_in[4];
  const float* b2 = (const float*)d_in[5];
  const float* Wg = (const float*)d_in[6];
  const float* bg = (const float*)d_in[7];

  char* ws = (char*)d_ws;
  const size_t FRAG_BYTES = (size_t)512 * 512 * 2;  // 512 KB each
  unsigned short* w1f  = (unsigned short*)(ws + 0 * FRAG_BYTES);
  unsigned short* w2f  = (unsigned short*)(ws + 1 * FRAG_BYTES);
  unsigned short* wgaf = (unsigned short*)(ws + 2 * FRAG_BYTES);
  unsigned short* wgbf = (unsigned short*)(ws + 3 * FRAG_BYTES);
  float*          c1   = (float*)(ws + 4 * FRAG_BYTES);

  pack_frags_kernel<<<128, 256, 0, stream>>>(W1, 513, 0,   w1f);
  pack_frags_kernel<<<128, 256, 0, stream>>>(W2, 512, 0,   w2f);
  pack_frags_kernel<<<128, 256, 0, stream>>>(Wg, 1024, 0,  wgaf);
  pack_frags_kernel<<<128, 256, 0, stream>>>(Wg, 1024, 512, wgbf);
  c1_kernel<<<1, 512, 0, stream>>>(W1, b1, c1);

  ode_fused<<<N_ROWS / 64, 1024, 0, stream>>>(x, h0, b2, bg,
                                              (const s16x8*)w1f, (const s16x8*)w2f,
                                              (const s16x8*)wgaf, (const s16x8*)wgbf,
                                              c1, (float*)d_out);
}

// Round 10
// 1054.382 us; speedup vs baseline: 1.9577x; 1.0285x over previous
//
#include <hip/hip_runtime.h>

#define N_ROWS 65536
#define DIM    512
#define NSTEP  10

typedef float  f32x16 __attribute__((ext_vector_type(16)));
typedef float  f32x4  __attribute__((ext_vector_type(4)));
typedef short  s16x8  __attribute__((ext_vector_type(8)));
typedef __bf16 bf16x8 __attribute__((ext_vector_type(8)));
typedef unsigned int u32x2 __attribute__((ext_vector_type(2)));
typedef unsigned int u32x4 __attribute__((ext_vector_type(4)));

__device__ __forceinline__ unsigned f2bf(float f) {
  unsigned u = __float_as_uint(f);
  return (u + 0x7fffu + ((u >> 16) & 1u)) >> 16;  // exact RNE fp32 -> bf16
}
// nearest rounding (ties away from zero), packed via v_perm
__device__ __forceinline__ unsigned pack2bf_rn(float a, float b) {
  unsigned ua = __float_as_uint(a) + 0x8000u;
  unsigned ub = __float_as_uint(b) + 0x8000u;
  return __builtin_amdgcn_perm(ub, ua, 0x07060302u);
}
#define LOG2E_X2 2.885390081777927f
#define LOG2E    1.442695040888963f
__device__ __forceinline__ float ftanh(float x) {   // 1 - 2/(1+2^(2x*log2e))
  float t = __builtin_amdgcn_exp2f(x * LOG2E_X2);
  float r = __builtin_amdgcn_rcpf(1.0f + t);
  return __builtin_fmaf(-2.0f, r, 1.0f);
}
__device__ __forceinline__ float fsigm(float x) {
  float t = __builtin_amdgcn_exp2f(-x * LOG2E);
  return __builtin_amdgcn_rcpf(1.0f + t);
}
__device__ __forceinline__ void mfma(f32x16& c, s16x8 a, s16x8 b) {
  c = __builtin_amdgcn_mfma_f32_32x32x16_bf16(
        __builtin_bit_cast(bf16x8, a), __builtin_bit_cast(bf16x8, b), c, 0, 0, 0);
}

// Pack a 512x512 slice of row-major fp32 weights into bf16 MFMA A-frags,
// OTG-MAJOR streams: frag f = otg*32 + ks holds
// A[o=otg*32+(l&31)][k=ks*16+8*(l>>5)+i], i=0..7.
__global__ void pack_frags_kernel(const float* __restrict__ src, int row_stride,
                                  int col_off, unsigned short* __restrict__ dst) {
  const int idx = blockIdx.x * 256 + threadIdx.x;  // 0..32767
  const int l    = idx & 63;
  const int frag = idx >> 6;        // otg*32 + ks
  const int otg  = frag >> 5;
  const int ks   = frag & 31;
  const int o = otg * 32 + (l & 31);
  const int k = ks * 16 + (l >> 5) * 8;
  const float* p = src + (size_t)o * row_stride + col_off + k;
  s16x8 v;
#pragma unroll
  for (int i = 0; i < 8; ++i) v[i] = (short)f2bf(p[i]);
  *reinterpret_cast<s16x8*>(dst + (size_t)idx * 8) = v;
}

// c1[s][o] = b1[o] + t_s * W1[o][512]   (time-column folded into step bias)
__global__ void c1_kernel(const float* __restrict__ W1, const float* __restrict__ b1,
                          float* __restrict__ c1) {
  const int o = threadIdx.x;  // 512 threads
  const float wt = W1[(size_t)o * 513 + 512];
  const float bb = b1[o];
  for (int s = 0; s < NSTEP; ++s)
    c1[s * DIM + o] = bb + ((float)s * 0.1f) * wt;
}

// 512 threads = 8 waves; wave w owns o-cols [64w,64w+64) (otg 2w,2w+1) x 64 m.
// LDS tile in B-frag layout: frag(ks,mt) @ ((ks*2+mt)<<10), lane l's 16B at
// l*16 holding tile[m=32mt+(l&31)][k=16ks+8*(l>>5)+i].
// mm_lds: 4 MFMA per B-read-pair (halves LDS traffic vs 2-frag waves), A
// register-pipelined depth 4 (prefetch ks+4 before ks's MFMAs).
__global__ __launch_bounds__(512, 2)
void ode_fused(const float* __restrict__ x, const float* __restrict__ h0,
               const float* __restrict__ b2, const float* __restrict__ bg,
               const s16x8* __restrict__ w1f, const s16x8* __restrict__ w2f,
               const s16x8* __restrict__ wgaf, const s16x8* __restrict__ wgbf,
               const float* __restrict__ c1, float* __restrict__ out)
{
  __shared__ char ldsT[64 * 1024];   // 64 frags of 1KB, in-place

  const int tid = threadIdx.x;
  const int w   = tid >> 6;          // wave 0..7
  const int l   = tid & 63;
  const int lm  = l & 31;
  const int h5  = l >> 5;
  const int m0  = blockIdx.x << 6;   // 64 rows per block
  const int ow  = w << 6;            // 64-wide o-column range
  const unsigned lbyte = (unsigned)l << 4;

  // ---------------- stage h0 -> ldsT in frag layout (8 frags/wave) --------
  {
#pragma unroll
    for (int q = 0; q < 8; ++q) {
      const int f  = (w << 3) | q;   // frag index = ks*2+mt
      const int ks = f >> 1;
      const int mt = f & 1;
      const float* src = h0 + (size_t)(m0 + (mt << 5) + lm) * DIM + (ks << 4) + (h5 << 3);
      f32x4 v0 = *reinterpret_cast<const f32x4*>(src);
      f32x4 v1 = *reinterpret_cast<const f32x4*>(src + 4);
      u32x4 pk;
      pk[0] = pack2bf_rn(v0[0], v0[1]); pk[1] = pack2bf_rn(v0[2], v0[3]);
      pk[2] = pack2bf_rn(v1[0], v1[1]); pk[3] = pack2bf_rn(v1[2], v1[3]);
      *reinterpret_cast<u32x4*>(ldsT + (f << 10) + lbyte) = pk;
    }
  }

  // ---------------- fp32 h state in acc layout ----------------
  // value (ot,mt,4g+j): m = m0+32*mt+lm, o = ow+32*ot+8g+4*h5+j
  f32x16 hst[2][2];
#pragma unroll
  for (int ot = 0; ot < 2; ++ot)
#pragma unroll
    for (int mt = 0; mt < 2; ++mt) {
      const float* hr = h0 + (size_t)(m0 + (mt << 5) + lm) * DIM;
#pragma unroll
      for (int g = 0; g < 4; ++g) {
        const int oc = ow + (ot << 5) + (g << 3) + (h5 << 2);
        f32x4 v = *reinterpret_cast<const f32x4*>(hr + oc);
#pragma unroll
        for (int j = 0; j < 4; ++j) hst[ot][mt][(g << 2) + j] = v[j];
      }
    }

  f32x16 acc[2][2];

  // acc[ot][mt] += W[o][k]*tile[m][k], K=512. A depth-4 register pipeline.
  auto mm_lds = [&](const s16x8* __restrict__ A) {
    const s16x8* A0 = A + (w << 12);   // otg=2w stream (32KB)
    const s16x8* A1 = A0 + 2048;       // otg=2w+1 stream
    s16x8 a0[4], a1[4];
#pragma unroll
    for (int i = 0; i < 4; ++i) { a0[i] = A0[(i << 6) + l]; a1[i] = A1[(i << 6) + l]; }
#pragma unroll 4
    for (int ks = 0; ks < 28; ++ks) {
      s16x8 ca0 = a0[ks & 3], ca1 = a1[ks & 3];
      a0[ks & 3] = A0[((ks + 4) << 6) + l];
      a1[ks & 3] = A1[((ks + 4) << 6) + l];
      s16x8 b0 = *reinterpret_cast<const s16x8*>(ldsT + (ks << 11) + lbyte);
      s16x8 b1 = *reinterpret_cast<const s16x8*>(ldsT + (ks << 11) + 1024 + lbyte);
      mfma(acc[0][0], ca0, b0);
      mfma(acc[0][1], ca0, b1);
      mfma(acc[1][0], ca1, b0);
      mfma(acc[1][1], ca1, b1);
    }
#pragma unroll
    for (int ks = 28; ks < 32; ++ks) {
      s16x8 ca0 = a0[ks & 3], ca1 = a1[ks & 3];
      s16x8 b0 = *reinterpret_cast<const s16x8*>(ldsT + (ks << 11) + lbyte);
      s16x8 b1 = *reinterpret_cast<const s16x8*>(ldsT + (ks << 11) + 1024 + lbyte);
      mfma(acc[0][0], ca0, b0);
      mfma(acc[0][1], ca0, b1);
      mfma(acc[1][0], ca1, b0);
      mfma(acc[1][1], ca1, b1);
    }
  };

  // broadcast per-o fp32 vector into acc
  auto acc_init = [&](const float* __restrict__ vec) {
#pragma unroll
    for (int ot = 0; ot < 2; ++ot)
#pragma unroll
      for (int g = 0; g < 4; ++g) {
        const int oc = ow + (ot << 5) + (g << 3) + (h5 << 2);
        f32x4 v = *reinterpret_cast<const f32x4*>(vec + oc);
#pragma unroll
        for (int mt = 0; mt < 2; ++mt)
#pragma unroll
          for (int j = 0; j < 4; ++j) acc[ot][mt][(g << 2) + j] = v[j];
      }
  };

  // write bf16(src) into frag layout (k-dim = wave's o-cols).
  // value (ot,mt,4g+j) -> frag(ks=4w+2ot+(g>>1), mt), lane lm+32*(g&1), byte 8*h5+4j'
  auto tile_write = [&](const f32x16 src[2][2]) {
    const unsigned base = ((unsigned)w << 13) + ((unsigned)lm << 4) + ((unsigned)h5 << 3);
#pragma unroll
    for (int ot = 0; ot < 2; ++ot)
#pragma unroll
      for (int mt = 0; mt < 2; ++mt)
#pragma unroll
        for (int g = 0; g < 4; ++g) {
          u32x2 pk;
          pk[0] = pack2bf_rn(src[ot][mt][(g << 2) + 0], src[ot][mt][(g << 2) + 1]);
          pk[1] = pack2bf_rn(src[ot][mt][(g << 2) + 2], src[ot][mt][(g << 2) + 3]);
          *reinterpret_cast<u32x2*>(ldsT + base + (ot << 12) + ((g >> 1) << 11)
                                    + (mt << 10) + ((g & 1) << 9)) = pk;
        }
  };

  __syncthreads();  // staged tile visible

#pragma unroll 1
  for (int s = 0; s < NSTEP; ++s) {
    // H1 = tanh(W1 . Z^T + c1_s)
    acc_init(c1 + s * DIM);
    mm_lds(w1f);
#pragma unroll
    for (int ot = 0; ot < 2; ++ot)
#pragma unroll
      for (int mt = 0; mt < 2; ++mt)
#pragma unroll
        for (int i = 0; i < 16; ++i) acc[ot][mt][i] = ftanh(acc[ot][mt][i]);
    __syncthreads();          // all reads of Z done
    tile_write(acc);          // overwrite in place with H1
    __syncthreads();          // H1 visible
    // h += dt * tanh(W2 . H1^T + b2)  == fma(-0.2, rcp(1+e^{2a}), h+0.1)
    acc_init(b2);
    mm_lds(w2f);
#pragma unroll
    for (int ot = 0; ot < 2; ++ot)
#pragma unroll
      for (int mt = 0; mt < 2; ++mt)
#pragma unroll
        for (int i = 0; i < 16; ++i) {
          float t = __builtin_amdgcn_exp2f(acc[ot][mt][i] * LOG2E_X2);
          float r = __builtin_amdgcn_rcpf(1.0f + t);
          hst[ot][mt][i] = __builtin_fmaf(-0.2f, r, hst[ot][mt][i] + 0.1f);
        }
    __syncthreads();          // all reads of H1 done
    tile_write(hst);          // overwrite in place with new h
    __syncthreads();          // h visible
  }

  // ---- gating: G = WgB . E^T + WgA . X^T + bg ----
  acc_init(bg);
  mm_lds(wgbf);        // evolved part (tile holds E)
  {
    const s16x8* A0 = wgaf + (w << 12);
    const s16x8* A1 = A0 + 2048;
    const float* xr0 = x + (size_t)(m0 + lm) * DIM + (h5 << 3);
    const float* xr1 = xr0 + (size_t)32 * DIM;
#pragma unroll 4
    for (int ks = 0; ks < 32; ++ks) {
      s16x8 a0 = A0[(ks << 6) + l];
      s16x8 a1 = A1[(ks << 6) + l];
      const int kc = ks << 4;
      f32x4 u0 = *reinterpret_cast<const f32x4*>(xr0 + kc);
      f32x4 u1 = *reinterpret_cast<const f32x4*>(xr0 + kc + 4);
      u32x4 pb;
      pb[0] = pack2bf_rn(u0[0], u0[1]); pb[1] = pack2bf_rn(u0[2], u0[3]);
      pb[2] = pack2bf_rn(u1[0], u1[1]); pb[3] = pack2bf_rn(u1[2], u1[3]);
      s16x8 b0 = __builtin_bit_cast(s16x8, pb);
      f32x4 w0 = *reinterpret_cast<const f32x4*>(xr1 + kc);
      f32x4 w1 = *reinterpret_cast<const f32x4*>(xr1 + kc + 4);
      u32x4 qb;
      qb[0] = pack2bf_rn(w0[0], w0[1]); qb[1] = pack2bf_rn(w0[2], w0[3]);
      qb[2] = pack2bf_rn(w1[0], w1[1]); qb[3] = pack2bf_rn(w1[2], w1[3]);
      s16x8 b1 = __builtin_bit_cast(s16x8, qb);
      mfma(acc[0][0], a0, b0);
      mfma(acc[0][1], a0, b1);
      mfma(acc[1][0], a1, b0);
      mfma(acc[1][1], a1, b1);
    }
  }

  // ---- blend + store both output copies ----
  float* out1 = out + (size_t)N_ROWS * DIM;
#pragma unroll
  for (int mt = 0; mt < 2; ++mt) {
    const int m = m0 + (mt << 5) + lm;
    const float* xr = x + (size_t)m * DIM;
    float* o0p = out  + (size_t)m * DIM;
    float* o1p = out1 + (size_t)m * DIM;
#pragma unroll
    for (int ot = 0; ot < 2; ++ot)
#pragma unroll
      for (int g = 0; g < 4; ++g) {
        const int oc = ow + (ot << 5) + (g << 3) + (h5 << 2);
        f32x4 xv = *reinterpret_cast<const f32x4*>(xr + oc);
        f32x4 r;
#pragma unroll
        for (int j = 0; j < 4; ++j) {
          const float gt = fsigm(acc[ot][mt][(g << 2) + j]);
          const float ev = hst[ot][mt][(g << 2) + j];
          r[j] = gt * ev + (1.0f - gt) * xv[j];
        }
        *reinterpret_cast<f32x4*>(o0p + oc) = r;
        *reinterpret_cast<f32x4*>(o1p + oc) = r;
      }
  }
}

extern "C" void kernel_launch(void* const* d_in, const int* in_sizes, int n_in,
                              void* d_out, int out_size, void* d_ws, size_t ws_size,
                              hipStream_t stream) {
  const float* x  = (const float*)d_in[0];
  const float* h0 = (const float*)d_in[1];
  const float* W1 = (const float*)d_in[2];
  const float* b1 = (const float*)d_in[3];
  const float* W2 = (const float*)d_in[4];
  const float* b2 = (const float*)d_in[5];
  const float* Wg = (const float*)d_in[6];
  const float* bg = (const float*)d_in[7];

  char* ws = (char*)d_ws;
  const size_t FRAG_BYTES = (size_t)512 * 512 * 2;  // 512 KB each
  unsigned short* w1f  = (unsigned short*)(ws + 0 * FRAG_BYTES);
  unsigned short* w2f  = (unsigned short*)(ws + 1 * FRAG_BYTES);
  unsigned short* wgaf = (unsigned short*)(ws + 2 * FRAG_BYTES);
  unsigned short* wgbf = (unsigned short*)(ws + 3 * FRAG_BYTES);
  float*          c1   = (float*)(ws + 4 * FRAG_BYTES);

  pack_frags_kernel<<<128, 256, 0, stream>>>(W1, 513, 0,   w1f);
  pack_frags_kernel<<<128, 256, 0, stream>>>(W2, 512, 0,   w2f);
  pack_frags_kernel<<<128, 256, 0, stream>>>(Wg, 1024, 0,  wgaf);
  pack_frags_kernel<<<128, 256, 0, stream>>>(Wg, 1024, 512, wgbf);
  c1_kernel<<<1, 512, 0, stream>>>(W1, b1, c1);

  ode_fused<<<N_ROWS / 64, 512, 0, stream>>>(x, h0, b2, bg,
                                             (const s16x8*)w1f, (const s16x8*)w2f,
                                             (const s16x8*)wgaf, (const s16x8*)wgbf,
                                             c1, (float*)d_out);
}

// Round 11
// 1001.727 us; speedup vs baseline: 2.0606x; 1.0526x over previous
//
#include <hip/hip_runtime.h>

#define N_ROWS 65536
#define DIM    512
#define NSTEP  10

typedef float  f32x16 __attribute__((ext_vector_type(16)));
typedef float  f32x4  __attribute__((ext_vector_type(4)));
typedef short  s16x8  __attribute__((ext_vector_type(8)));
typedef __bf16 bf16x8 __attribute__((ext_vector_type(8)));
typedef unsigned int u32x2 __attribute__((ext_vector_type(2)));
typedef unsigned int u32x4 __attribute__((ext_vector_type(4)));

__device__ __forceinline__ unsigned f2bf(float f) {
  unsigned u = __float_as_uint(f);
  return (u + 0x7fffu + ((u >> 16) & 1u)) >> 16;  // exact RNE fp32 -> bf16
}
// nearest rounding (ties away from zero), packed via v_perm
__device__ __forceinline__ unsigned pack2bf_rn(float a, float b) {
  unsigned ua = __float_as_uint(a) + 0x8000u;
  unsigned ub = __float_as_uint(b) + 0x8000u;
  return __builtin_amdgcn_perm(ub, ua, 0x07060302u);
}
#define LOG2E_X2 2.885390081777927f
#define LOG2E    1.442695040888963f
__device__ __forceinline__ float ftanh(float x) {   // 1 - 2/(1+2^(2x*log2e))
  float t = __builtin_amdgcn_exp2f(x * LOG2E_X2);
  float r = __builtin_amdgcn_rcpf(1.0f + t);
  return __builtin_fmaf(-2.0f, r, 1.0f);
}
__device__ __forceinline__ float fsigm(float x) {
  float t = __builtin_amdgcn_exp2f(-x * LOG2E);
  return __builtin_amdgcn_rcpf(1.0f + t);
}
__device__ __forceinline__ void mfma(f32x16& c, s16x8 a, s16x8 b) {
  c = __builtin_amdgcn_mfma_f32_32x32x16_bf16(
        __builtin_bit_cast(bf16x8, a), __builtin_bit_cast(bf16x8, b), c, 0, 0, 0);
}

// Pack a 512x512 slice of row-major fp32 weights into bf16 MFMA A-frags,
// OTG-MAJOR streams: frag f = otg*32 + ks holds
// A[o=otg*32+(l&31)][k=ks*16+8*(l>>5)+i], i=0..7.
__global__ void pack_frags_kernel(const float* __restrict__ src, int row_stride,
                                  int col_off, unsigned short* __restrict__ dst) {
  const int idx = blockIdx.x * 256 + threadIdx.x;  // 0..32767
  const int l    = idx & 63;
  const int frag = idx >> 6;        // otg*32 + ks
  const int otg  = frag >> 5;
  const int ks   = frag & 31;
  const int o = otg * 32 + (l & 31);
  const int k = ks * 16 + (l >> 5) * 8;
  const float* p = src + (size_t)o * row_stride + col_off + k;
  s16x8 v;
#pragma unroll
  for (int i = 0; i < 8; ++i) v[i] = (short)f2bf(p[i]);
  *reinterpret_cast<s16x8*>(dst + (size_t)idx * 8) = v;
}

// c1[s][o] = b1[o] + t_s * W1[o][512]   (time-column folded into step bias)
__global__ void c1_kernel(const float* __restrict__ W1, const float* __restrict__ b1,
                          float* __restrict__ c1) {
  const int o = threadIdx.x;  // 512 threads
  const float wt = W1[(size_t)o * 513 + 512];
  const float bb = b1[o];
  for (int s = 0; s < NSTEP; ++s)
    c1[s * DIM + o] = bb + ((float)s * 0.1f) * wt;
}

// 512 threads = 8 waves; wave w owns o-cols [64w,64w+64) (otg 2w,2w+1) x 64 m.
// Double-buffered LDS tiles in B-frag layout: frag(ks,mt) @ ((ks*2+mt)<<10),
// lane l's 16B at l*16 holding tile[m=32mt+(l&31)][k=16ks+8*(l>>5)+i].
// K-loop: rolled unroll-4, no explicit staging (R8/R10 spill lesson).
__global__ __launch_bounds__(512, 2)
void ode_fused(const float* __restrict__ x, const float* __restrict__ h0,
               const float* __restrict__ b2, const float* __restrict__ bg,
               const s16x8* __restrict__ w1f, const s16x8* __restrict__ w2f,
               const s16x8* __restrict__ wgaf, const s16x8* __restrict__ wgbf,
               const float* __restrict__ c1, float* __restrict__ out)
{
  __shared__ char ldsA[64 * 1024];   // 64 frags of 1KB each
  __shared__ char ldsB[64 * 1024];

  const int tid = threadIdx.x;
  const int w   = tid >> 6;          // wave 0..7
  const int l   = tid & 63;
  const int lm  = l & 31;
  const int h5  = l >> 5;
  const int m0  = blockIdx.x << 6;   // 64 rows per block
  const int ow  = w << 6;            // 64-wide o-column range
  const unsigned lbyte = (unsigned)l << 4;

  // ---------------- stage h0 -> ldsA in frag layout (8 frags/wave) --------
  {
#pragma unroll
    for (int q = 0; q < 8; ++q) {
      const int f  = (w << 3) | q;   // frag index = ks*2+mt
      const int ks = f >> 1;
      const int mt = f & 1;
      const float* src = h0 + (size_t)(m0 + (mt << 5) + lm) * DIM + (ks << 4) + (h5 << 3);
      f32x4 v0 = *reinterpret_cast<const f32x4*>(src);
      f32x4 v1 = *reinterpret_cast<const f32x4*>(src + 4);
      u32x4 pk;
      pk[0] = pack2bf_rn(v0[0], v0[1]); pk[1] = pack2bf_rn(v0[2], v0[3]);
      pk[2] = pack2bf_rn(v1[0], v1[1]); pk[3] = pack2bf_rn(v1[2], v1[3]);
      *reinterpret_cast<u32x4*>(ldsA + (f << 10) + lbyte) = pk;
    }
  }

  // ---------------- fp32 h state in acc layout ----------------
  // value (ot,mt,4g+j): m = m0+32*mt+lm, o = ow+32*ot+8g+4*h5+j
  f32x16 hst[2][2];
#pragma unroll
  for (int ot = 0; ot < 2; ++ot)
#pragma unroll
    for (int mt = 0; mt < 2; ++mt) {
      const float* hr = h0 + (size_t)(m0 + (mt << 5) + lm) * DIM;
#pragma unroll
      for (int g = 0; g < 4; ++g) {
        const int oc = ow + (ot << 5) + (g << 3) + (h5 << 2);
        f32x4 v = *reinterpret_cast<const f32x4*>(hr + oc);
#pragma unroll
        for (int j = 0; j < 4; ++j) hst[ot][mt][(g << 2) + j] = v[j];
      }
    }

  f32x16 acc[2][2];

  // acc[ot][mt] += W[o][k]*tile[m][k], K=512. Rolled, address-free.
  auto mm_lds = [&](const s16x8* __restrict__ A, const char* __restrict__ buf) {
    const s16x8* A0 = A + (w << 12);   // otg=2w stream (32KB)
    const s16x8* A1 = A0 + 2048;       // otg=2w+1 stream
#pragma unroll 4
    for (int ks = 0; ks < 32; ++ks) {
      s16x8 a0 = A0[(ks << 6) + l];
      s16x8 a1 = A1[(ks << 6) + l];
      s16x8 b0 = *reinterpret_cast<const s16x8*>(buf + (ks << 11) + lbyte);
      s16x8 b1 = *reinterpret_cast<const s16x8*>(buf + (ks << 11) + 1024 + lbyte);
      mfma(acc[0][0], a0, b0);
      mfma(acc[0][1], a0, b1);
      mfma(acc[1][0], a1, b0);
      mfma(acc[1][1], a1, b1);
    }
  };

  // broadcast per-o fp32 vector into acc
  auto acc_init = [&](const float* __restrict__ vec) {
#pragma unroll
    for (int ot = 0; ot < 2; ++ot)
#pragma unroll
      for (int g = 0; g < 4; ++g) {
        const int oc = ow + (ot << 5) + (g << 3) + (h5 << 2);
        f32x4 v = *reinterpret_cast<const f32x4*>(vec + oc);
#pragma unroll
        for (int mt = 0; mt < 2; ++mt)
#pragma unroll
          for (int j = 0; j < 4; ++j) acc[ot][mt][(g << 2) + j] = v[j];
      }
  };

  // write bf16(src) into frag layout (k-dim = wave's o-cols).
  // value (ot,mt,4g+j) -> frag(ks=4w+2ot+(g>>1), mt), lane lm+32*(g&1), byte 8*h5
  auto tile_write = [&](const f32x16 src[2][2], char* __restrict__ buf) {
    const unsigned base = ((unsigned)w << 13) + ((unsigned)lm << 4) + ((unsigned)h5 << 3);
#pragma unroll
    for (int ot = 0; ot < 2; ++ot)
#pragma unroll
      for (int mt = 0; mt < 2; ++mt)
#pragma unroll
        for (int g = 0; g < 4; ++g) {
          u32x2 pk;
          pk[0] = pack2bf_rn(src[ot][mt][(g << 2) + 0], src[ot][mt][(g << 2) + 1]);
          pk[1] = pack2bf_rn(src[ot][mt][(g << 2) + 2], src[ot][mt][(g << 2) + 3]);
          *reinterpret_cast<u32x2*>(buf + base + (ot << 12) + ((g >> 1) << 11)
                                    + (mt << 10) + ((g & 1) << 9)) = pk;
        }
  };

  __syncthreads();  // staged tile visible

#pragma unroll 1
  for (int s = 0; s < NSTEP; ++s) {
    // H1 = tanh(W1 . Z^T + c1_s)     (read A, write B)
    acc_init(c1 + s * DIM);
    mm_lds(w1f, ldsA);
#pragma unroll
    for (int ot = 0; ot < 2; ++ot)
#pragma unroll
      for (int mt = 0; mt < 2; ++mt)
#pragma unroll
        for (int i = 0; i < 16; ++i) acc[ot][mt][i] = ftanh(acc[ot][mt][i]);
    tile_write(acc, ldsB);
    __syncthreads();          // B complete; everyone's A-reads already done
    // h += dt * tanh(W2 . H1^T + b2)  (read B, write A)
    acc_init(b2);
    mm_lds(w2f, ldsB);
#pragma unroll
    for (int ot = 0; ot < 2; ++ot)
#pragma unroll
      for (int mt = 0; mt < 2; ++mt)
#pragma unroll
        for (int i = 0; i < 16; ++i) {
          float t = __builtin_amdgcn_exp2f(acc[ot][mt][i] * LOG2E_X2);
          float r = __builtin_amdgcn_rcpf(1.0f + t);
          hst[ot][mt][i] = __builtin_fmaf(-0.2f, r, hst[ot][mt][i] + 0.1f);
        }
    tile_write(hst, ldsA);
    __syncthreads();          // A complete
  }

  // ---- gating: G = WgB . E^T + WgA . X^T + bg ----
  acc_init(bg);
  mm_lds(wgbf, ldsA);  // evolved part (ldsA holds E)
  {
    const s16x8* A0 = wgaf + (w << 12);
    const s16x8* A1 = A0 + 2048;
    const float* xr0 = x + (size_t)(m0 + lm) * DIM + (h5 << 3);
    const float* xr1 = xr0 + (size_t)32 * DIM;
#pragma unroll 2
    for (int ks = 0; ks < 32; ++ks) {
      s16x8 a0 = A0[(ks << 6) + l];
      s16x8 a1 = A1[(ks << 6) + l];
      const int kc = ks << 4;
      f32x4 u0 = *reinterpret_cast<const f32x4*>(xr0 + kc);
      f32x4 u1 = *reinterpret_cast<const f32x4*>(xr0 + kc + 4);
      u32x4 pb;
      pb[0] = pack2bf_rn(u0[0], u0[1]); pb[1] = pack2bf_rn(u0[2], u0[3]);
      pb[2] = pack2bf_rn(u1[0], u1[1]); pb[3] = pack2bf_rn(u1[2], u1[3]);
      s16x8 b0 = __builtin_bit_cast(s16x8, pb);
      f32x4 w0 = *reinterpret_cast<const f32x4*>(xr1 + kc);
      f32x4 w1 = *reinterpret_cast<const f32x4*>(xr1 + kc + 4);
      u32x4 qb;
      qb[0] = pack2bf_rn(w0[0], w0[1]); qb[1] = pack2bf_rn(w0[2], w0[3]);
      qb[2] = pack2bf_rn(w1[0], w1[1]); qb[3] = pack2bf_rn(w1[2], w1[3]);
      s16x8 b1 = __builtin_bit_cast(s16x8, qb);
      mfma(acc[0][0], a0, b0);
      mfma(acc[0][1], a0, b1);
      mfma(acc[1][0], a1, b0);
      mfma(acc[1][1], a1, b1);
    }
  }

  // ---- blend + store both output copies ----
  float* out1 = out + (size_t)N_ROWS * DIM;
#pragma unroll
  for (int mt = 0; mt < 2; ++mt) {
    const int m = m0 + (mt << 5) + lm;
    const float* xr = x + (size_t)m * DIM;
    float* o0p = out  + (size_t)m * DIM;
    float* o1p = out1 + (size_t)m * DIM;
#pragma unroll
    for (int ot = 0; ot < 2; ++ot)
#pragma unroll
      for (int g = 0; g < 4; ++g) {
        const int oc = ow + (ot << 5) + (g << 3) + (h5 << 2);
        f32x4 xv = *reinterpret_cast<const f32x4*>(xr + oc);
        f32x4 r;
#pragma unroll
        for (int j = 0; j < 4; ++j) {
          const float gt = fsigm(acc[ot][mt][(g << 2) + j]);
          const float ev = hst[ot][mt][(g << 2) + j];
          r[j] = gt * ev + (1.0f - gt) * xv[j];
        }
        *reinterpret_cast<f32x4*>(o0p + oc) = r;
        *reinterpret_cast<f32x4*>(o1p + oc) = r;
      }
  }
}

extern "C" void kernel_launch(void* const* d_in, const int* in_sizes, int n_in,
                              void* d_out, int out_size, void* d_ws, size_t ws_size,
                              hipStream_t stream) {
  const float* x  = (const float*)d_in[0];
  const float* h0 = (const float*)d_in[1];
  const float* W1 = (const float*)d_in[2];
  const float* b1 = (const float*)d_in[3];
  const float* W2 = (const float*)d_in[4];
  const float* b2 = (const float*)d_in[5];
  const float* Wg = (const float*)d_in[6];
  const float* bg = (const float*)d_in[7];

  char* ws = (char*)d_ws;
  const size_t FRAG_BYTES = (size_t)512 * 512 * 2;  // 512 KB each
  unsigned short* w1f  = (unsigned short*)(ws + 0 * FRAG_BYTES);
  unsigned short* w2f  = (unsigned short*)(ws + 1 * FRAG_BYTES);
  unsigned short* wgaf = (unsigned short*)(ws + 2 * FRAG_BYTES);
  unsigned short* wgbf = (unsigned short*)(ws + 3 * FRAG_BYTES);
  float*          c1   = (float*)(ws + 4 * FRAG_BYTES);

  pack_frags_kernel<<<128, 256, 0, stream>>>(W1, 513, 0,   w1f);
  pack_frags_kernel<<<128, 256, 0, stream>>>(W2, 512, 0,   w2f);
  pack_frags_kernel<<<128, 256, 0, stream>>>(Wg, 1024, 0,  wgaf);
  pack_frags_kernel<<<128, 256, 0, stream>>>(Wg, 1024, 512, wgbf);
  c1_kernel<<<1, 512, 0, stream>>>(W1, b1, c1);

  ode_fused<<<N_ROWS / 64, 512, 0, stream>>>(x, h0, b2, bg,
                                             (const s16x8*)w1f, (const s16x8*)w2f,
                                             (const s16x8*)wgaf, (const s16x8*)wgbf,
                                             c1, (float*)d_out);
}